// Round 8
// baseline (43.417 us; speedup 1.0000x reference)
//
#include <hip/hip_runtime.h>
#include <hip/hip_cooperative_groups.h>
#include <math.h>

namespace cg = cooperative_groups;

constexpr int BB  = 256;   // batch rows
constexpr int SS  = 512;   // slate size
constexpr int SP2 = SS + 2;

typedef float f32x2 __attribute__((ext_vector_type(2)));

__device__ __forceinline__ float sigmoidf_(float x) {
    return 1.0f / (1.0f + expf(-x));   // saturates cleanly to 0/1 in fp32
}

__global__ __launch_bounds__(512)
void ndcg_coop_kernel(const float* __restrict__ y_pred,
                      const float* __restrict__ y_true,
                      const int*   __restrict__ qid,
                      const int*   __restrict__ indices,
                      const int*   __restrict__ num_pos,
                      const int*   __restrict__ num_item,
                      const float* __restrict__ ideal_dcg,
                      const float* __restrict__ u_buf,
                      const float* __restrict__ v_buf,
                      const float* __restrict__ lambda_q,
                      const float* __restrict__ r_q,
                      const float* __restrict__ s_q,
                      float2* __restrict__ ws,
                      float* __restrict__ out) {
    __shared__ float sh_ys[SS] __attribute__((aligned(16)));  // yp, -1e4 at padded
    __shared__ float sm[64];

    const int b = blockIdx.x;
    const int t = threadIdx.x;          // one item per thread, 8 waves = 2/SIMD
    const int wid  = t >> 6;
    const int lane = t & 63;

    // ---- stage (coalesced dword loads) ----
    const float yt = y_true[b * SS + t];
    const float yp = y_pred[b * SS + t];
    const int   qd = qid[b * SS + t];
    const int   ix = indices[b * SS + t];

    const bool  fi = (yt != -1.0f);
    const float f  = fi ? 1.0f : 0.0f;
    sh_ys[t] = fi ? yp : -1.0e4f;
    const float G  = fi ? (exp2f(fmaxf(yt, 0.0f)) - 1.0f) : 0.0f;

    // ---- prefetch everything phase-C/t0 needs (in flight during hinge) ----
    const int   ui    = (qd + 1) * SP2 + (ix + 1);
    const float u_old = u_buf[ui];
    const float v_old = v_buf[ui];
    const int   qb    = qid[b * SS] + 1;
    const float lam   = lambda_q[qb];
    const float ni    = (float)num_item[b];
    const float sqv   = s_q[qb];
    const float rqv   = r_q[qb];
    const float npb   = (float)num_pos[b];
    const float idcgb = ideal_dcg[b];

    __syncthreads();

    // ---- n_fin + jmax in ONE roundtrip (float-encoded index, exact) ----
    float n_fin;
    int   jmax;
    {
        float v = f;
        float m = fi ? (float)t : -1.0f;
        #pragma unroll
        for (int off = 32; off > 0; off >>= 1) {
            v += __shfl_down(v, off, 64);
            m  = fmaxf(m, __shfl_down(m, off, 64));
        }
        if (lane == 0) { sm[wid] = v; sm[8 + wid] = m; }
        __syncthreads();
        n_fin = ((sm[0] + sm[1]) + (sm[2] + sm[3]))
              + ((sm[4] + sm[5]) + (sm[6] + sm[7]));
        jmax  = (int)fmaxf(fmaxf(fmaxf(sm[8],  sm[9]),  fmaxf(sm[10], sm[11])),
                           fmaxf(fmaxf(sm[12], sm[13]), fmaxf(sm[14], sm[15])));
    }
    const int j4cnt = (jmax + 4) >> 2;    // ceil((jmax+1)/4), block-uniform

    // ---- pairwise squared hinge: packed fp32, one item/thread ----
    const f32x2 yb = (f32x2)(1.0f - f * yp);    // d = yp[j] - yp[i] + 1
    const f32x2 z2 = (f32x2)0.0f;
    const float4* ys4 = (const float4*)sh_ys;
    f32x2 a0 = z2, a1 = z2;
    #pragma unroll 4
    for (int j = 0; j < j4cnt; ++j) {           // uniform-address LDS broadcast
        const float4 y = ys4[j];
        const f32x2 lo = {y.x, y.y};
        const f32x2 hi = {y.z, y.w};
        f32x2 d;
        d = __builtin_elementwise_max(lo + yb, z2); a0 = __builtin_elementwise_fma(d, d, a0);
        d = __builtin_elementwise_max(hi + yb, z2); a1 = __builtin_elementwise_fma(d, d, a1);
    }
    const float inv_nfin = 1.0f / n_fin;
    const float g = f * (((a0.x + a0.y) + (a1.x + a1.y)) * inv_nfin) + 1e-10f;

    // ---- per-item phase-C terms ----
    const float nug   = u_old - g;                 // u_old - stopgrad(g)
    const float v_new = 0.9f * v_old + 0.1f * nug; // GAMMA_V
    const float g_u   = u_old - 0.01f * v_new;     // u_new (ETA1)
    const float t2    = fmaf(ni, g_u, 2.0f);       // 2 + ni*g_u (>0)
    const float l2t   = log2f(t2);
    const float rl2t  = 1.0f / l2t;

    float nfg = G * ni / (l2t * l2t * t2 * 0.6931471805599453f);

    const float pld  = fi ? (yp - lam) : 0.0f;
    const float sig1 = sigmoidf_(pld * 1000.0f);   // pld / TAU1
    const float siga = sigmoidf_(pld * 2.0f);      // pld * SIG_ALPHA
    nfg *= 2.0f * siga;                             // C_SIG * sig_a
    const float w1  = 2.0f * siga * (1.0f - siga);
    const float tt  = sig1 * (1.0f - sig1) * 1000.0f;  // /TAU1
    const float fgu = -G * rl2t;
    const float ypz = f * yp;

    // ---- six sums, ONE roundtrip; only t==0 consumes ----
    float c0 = f * tt;                 // Shess
    float c1 = f * (G * rl2t);         // Sphi
    float c2 = f * tt * ypz;           // Shy
    float c3 = nfg * g;                // P1
    float c4 = w1 * fgu * ypz;         // P2
    float c5 = w1 * fgu;               // P3
    #pragma unroll
    for (int off = 32; off > 0; off >>= 1) {
        c0 += __shfl_down(c0, off, 64);
        c1 += __shfl_down(c1, off, 64);
        c2 += __shfl_down(c2, off, 64);
        c3 += __shfl_down(c3, off, 64);
        c4 += __shfl_down(c4, off, 64);
        c5 += __shfl_down(c5, off, 64);
    }
    __syncthreads();                   // sm reuse (n_fin roundtrip done)
    if (lane == 0) {
        sm[wid]      = c0; sm[8 + wid]  = c1; sm[16 + wid] = c2;
        sm[24 + wid] = c3; sm[32 + wid] = c4; sm[40 + wid] = c5;
    }
    __syncthreads();

    if (t == 0) {
        float S[6];
        #pragma unroll
        for (int ch = 0; ch < 6; ++ch) {
            const float* p = &sm[8 * ch];
            S[ch] = ((p[0] + p[1]) + (p[2] + p[3]))
                  + ((p[4] + p[5]) + (p[6] + p[7]));
        }
        const float L_hess  = 1e-4f + S[0] * inv_nfin;             // TAU2 + ...
        const float nsp     = L_hess * sqv + S[1] * inv_nfin;
        const float r_new   = 0.9f * rqv + 0.1f * nsp;             // GAMMA_R
        const float s_new   = sqv - 0.01f * r_new;                 // ETA1
        const float hess    = (S[2] * inv_nfin) / s_new;
        const float row_sum = S[3] + S[4] - hess * S[5];
        ws[b] = make_float2(row_sum * (1.0f / (float)SS),
                            npb / (idcgb + 1e-10f));
    }

    // ---- runtime-vetted grid barrier (correct cross-XCD visibility) ----
    cg::this_grid().sync();

    // ---- block 0, wave 0: fixed-order final reduction ----
    if (b == 0 && t < 64) {
        float r = 0.f, a = 0.f;
        #pragma unroll
        for (int k = 0; k < 4; ++k) {
            const float2 p = ws[t + 64 * k];
            r += p.x; a += p.y;
        }
        #pragma unroll
        for (int off = 32; off > 0; off >>= 1) {
            r += __shfl_down(r, off, 64);
            a += __shfl_down(a, off, 64);
        }
        if (t == 0)
            out[0] = (a * (1.0f / (float)BB)) * (r * (1.0f / (float)BB));
    }
}

extern "C" void kernel_launch(void* const* d_in, const int* in_sizes, int n_in,
                              void* d_out, int out_size, void* d_ws, size_t ws_size,
                              hipStream_t stream) {
    const float* y_pred    = (const float*)d_in[0];
    const float* y_true    = (const float*)d_in[1];
    const int*   qid       = (const int*)  d_in[2];
    const int*   indices   = (const int*)  d_in[3];
    const int*   num_pos   = (const int*)  d_in[4];
    const int*   num_item  = (const int*)  d_in[5];
    const float* ideal_dcg = (const float*)d_in[6];
    const float* u_buf     = (const float*)d_in[7];
    const float* v_buf     = (const float*)d_in[8];
    const float* lambda_q  = (const float*)d_in[9];
    // d_in[10] = z_q (unused by the forward path)
    const float* r_q       = (const float*)d_in[11];
    const float* s_q       = (const float*)d_in[12];

    float2* ws  = (float2*)d_ws;   // [BB] per-row {row_mean, num_pos/idcg}
    float*  out = (float*)d_out;

    void* args[] = { (void*)&y_pred, (void*)&y_true, (void*)&qid, (void*)&indices,
                     (void*)&num_pos, (void*)&num_item, (void*)&ideal_dcg,
                     (void*)&u_buf, (void*)&v_buf, (void*)&lambda_q,
                     (void*)&r_q, (void*)&s_q, (void*)&ws, (void*)&out };

    hipLaunchCooperativeKernel((void*)ndcg_coop_kernel, dim3(BB), dim3(512),
                               args, 0, stream);
}

// Round 9
// 14.319 us; speedup vs baseline: 3.0321x; 3.0321x over previous
//
#include <hip/hip_runtime.h>
#include <math.h>

constexpr int BB  = 256;   // batch rows
constexpr int SS  = 512;   // slate size
constexpr int SP2 = SS + 2;

typedef float f32x2 __attribute__((ext_vector_type(2)));

__device__ __forceinline__ float sigmoidf_(float x) {
    return 1.0f / (1.0f + expf(-x));   // saturates cleanly to 0/1 in fp32
}

__global__ __launch_bounds__(512)
void ndcg_row_kernel(const float* __restrict__ y_pred,
                     const float* __restrict__ y_true,
                     const int*   __restrict__ qid,
                     const int*   __restrict__ indices,
                     const int*   __restrict__ num_pos,
                     const int*   __restrict__ num_item,
                     const float* __restrict__ ideal_dcg,
                     const float* __restrict__ u_buf,
                     const float* __restrict__ v_buf,
                     const float* __restrict__ lambda_q,
                     const float* __restrict__ r_q,
                     const float* __restrict__ s_q,
                     float2* __restrict__ ws) {
    __shared__ float sh_ys[SS] __attribute__((aligned(16)));  // yp, -1e4 at padded
    __shared__ float sm[64];   // [0:16) n_fin/jmax partials, [16:64) six-sum partials

    const int b = blockIdx.x;
    const int t = threadIdx.x;          // one item per thread, 8 waves = 2/SIMD
    const int wid  = t >> 6;
    const int lane = t & 63;

    // ---- stage (coalesced dword loads) ----
    const float yt = y_true[b * SS + t];
    const float yp = y_pred[b * SS + t];
    const int   qd = qid[b * SS + t];
    const int   ix = indices[b * SS + t];

    const bool  fi = (yt != -1.0f);
    const float f  = fi ? 1.0f : 0.0f;
    sh_ys[t] = fi ? yp : -1.0e4f;
    const float G  = fi ? (exp2f(fmaxf(yt, 0.0f)) - 1.0f) : 0.0f;

    // ---- wave-level n_fin/jmax partials BEFORE the barrier (registers only) ----
    {
        float v = f;
        float m = fi ? (float)t : -1.0f;
        #pragma unroll
        for (int off = 32; off > 0; off >>= 1) {
            v += __shfl_down(v, off, 64);
            m  = fmaxf(m, __shfl_down(m, off, 64));
        }
        if (lane == 0) { sm[wid] = v; sm[8 + wid] = m; }
    }

    // ---- prefetch everything phase-C/t0 needs (in flight across the barrier) ----
    const int   ui    = (qd + 1) * SP2 + (ix + 1);
    const float u_old = u_buf[ui];
    const float v_old = v_buf[ui];
    const int   qb    = qid[b * SS] + 1;
    const float lam   = lambda_q[qb];
    const float ni    = (float)num_item[b];
    const float sqv   = s_q[qb];
    const float rqv   = r_q[qb];
    const float npb   = (float)num_pos[b];
    const float idcgb = ideal_dcg[b];

    __syncthreads();   // publishes sh_ys AND sm[0:16) in one rendezvous

    const float n_fin = ((sm[0] + sm[1]) + (sm[2] + sm[3]))
                      + ((sm[4] + sm[5]) + (sm[6] + sm[7]));
    const int   jmax  = (int)fmaxf(fmaxf(fmaxf(sm[8],  sm[9]),  fmaxf(sm[10], sm[11])),
                                   fmaxf(fmaxf(sm[12], sm[13]), fmaxf(sm[14], sm[15])));
    const int j4cnt = (jmax + 4) >> 2;    // ceil((jmax+1)/4), block-uniform

    // ---- pairwise squared hinge: packed fp32, one item/thread ----
    const f32x2 yb = (f32x2)(1.0f - f * yp);    // d = yp[j] - yp[i] + 1
    const f32x2 z2 = (f32x2)0.0f;
    const float4* ys4 = (const float4*)sh_ys;
    f32x2 a0 = z2, a1 = z2;
    #pragma unroll 4
    for (int j = 0; j < j4cnt; ++j) {           // uniform-address LDS broadcast
        const float4 y = ys4[j];
        const f32x2 lo = {y.x, y.y};
        const f32x2 hi = {y.z, y.w};
        f32x2 d;
        d = __builtin_elementwise_max(lo + yb, z2); a0 = __builtin_elementwise_fma(d, d, a0);
        d = __builtin_elementwise_max(hi + yb, z2); a1 = __builtin_elementwise_fma(d, d, a1);
    }
    const float inv_nfin = 1.0f / n_fin;
    const float g = f * (((a0.x + a0.y) + (a1.x + a1.y)) * inv_nfin) + 1e-10f;

    // ---- per-item phase-C terms ----
    const float nug   = u_old - g;                 // u_old - stopgrad(g)
    const float v_new = 0.9f * v_old + 0.1f * nug; // GAMMA_V
    const float g_u   = u_old - 0.01f * v_new;     // u_new (ETA1)
    const float t2    = fmaf(ni, g_u, 2.0f);       // 2 + ni*g_u (>0)
    const float l2t   = log2f(t2);
    const float rl2t  = 1.0f / l2t;

    float nfg = G * ni / (l2t * l2t * t2 * 0.6931471805599453f);

    const float pld  = fi ? (yp - lam) : 0.0f;
    const float sig1 = sigmoidf_(pld * 1000.0f);   // pld / TAU1
    const float siga = sigmoidf_(pld * 2.0f);      // pld * SIG_ALPHA
    nfg *= 2.0f * siga;                             // C_SIG * sig_a
    const float w1  = 2.0f * siga * (1.0f - siga);
    const float tt  = sig1 * (1.0f - sig1) * 1000.0f;  // /TAU1
    const float fgu = -G * rl2t;
    const float ypz = f * yp;

    // ---- six sums, one roundtrip into the DISJOINT sm[16:64) region ----
    float c0 = f * tt;                 // Shess
    float c1 = f * (G * rl2t);         // Sphi
    float c2 = f * tt * ypz;           // Shy
    float c3 = nfg * g;                // P1
    float c4 = w1 * fgu * ypz;         // P2
    float c5 = w1 * fgu;               // P3
    #pragma unroll
    for (int off = 32; off > 0; off >>= 1) {
        c0 += __shfl_down(c0, off, 64);
        c1 += __shfl_down(c1, off, 64);
        c2 += __shfl_down(c2, off, 64);
        c3 += __shfl_down(c3, off, 64);
        c4 += __shfl_down(c4, off, 64);
        c5 += __shfl_down(c5, off, 64);
    }
    if (lane == 0) {                   // disjoint region: no anti-reuse barrier
        sm[16 + wid] = c0; sm[24 + wid] = c1; sm[32 + wid] = c2;
        sm[40 + wid] = c3; sm[48 + wid] = c4; sm[56 + wid] = c5;
    }
    __syncthreads();

    if (t == 0) {
        float S[6];
        #pragma unroll
        for (int ch = 0; ch < 6; ++ch) {
            const float* p = &sm[16 + 8 * ch];
            S[ch] = ((p[0] + p[1]) + (p[2] + p[3]))
                  + ((p[4] + p[5]) + (p[6] + p[7]));
        }
        const float L_hess  = 1e-4f + S[0] * inv_nfin;             // TAU2 + ...
        const float nsp     = L_hess * sqv + S[1] * inv_nfin;
        const float r_new   = 0.9f * rqv + 0.1f * nsp;             // GAMMA_R
        const float s_new   = sqv - 0.01f * r_new;                 // ETA1
        const float hess    = (S[2] * inv_nfin) / s_new;
        const float row_sum = S[3] + S[4] - hess * S[5];
        ws[b] = make_float2(row_sum * (1.0f / (float)SS),
                            npb / (idcgb + 1e-10f));
    }
}

__global__ __launch_bounds__(64)
void ndcg_final_kernel(const float2* __restrict__ ws, float* __restrict__ out) {
    const int t = threadIdx.x;     // single wave: no LDS, no syncthreads
    float r = 0.f, a = 0.f;
    #pragma unroll
    for (int k = 0; k < 4; ++k) {
        const float2 p = ws[t + 64 * k];
        r += p.x; a += p.y;
    }
    #pragma unroll
    for (int off = 32; off > 0; off >>= 1) {
        r += __shfl_down(r, off, 64);
        a += __shfl_down(a, off, 64);
    }
    if (t == 0)
        out[0] = (a * (1.0f / (float)BB)) * (r * (1.0f / (float)BB));
}

extern "C" void kernel_launch(void* const* d_in, const int* in_sizes, int n_in,
                              void* d_out, int out_size, void* d_ws, size_t ws_size,
                              hipStream_t stream) {
    const float* y_pred    = (const float*)d_in[0];
    const float* y_true    = (const float*)d_in[1];
    const int*   qid       = (const int*)  d_in[2];
    const int*   indices   = (const int*)  d_in[3];
    const int*   num_pos   = (const int*)  d_in[4];
    const int*   num_item  = (const int*)  d_in[5];
    const float* ideal_dcg = (const float*)d_in[6];
    const float* u_buf     = (const float*)d_in[7];
    const float* v_buf     = (const float*)d_in[8];
    const float* lambda_q  = (const float*)d_in[9];
    // d_in[10] = z_q (unused by the forward path)
    const float* r_q       = (const float*)d_in[11];
    const float* s_q       = (const float*)d_in[12];

    float2* ws = (float2*)d_ws;   // [BB] per-row {row_mean, num_pos/idcg}

    ndcg_row_kernel<<<BB, 512, 0, stream>>>(y_pred, y_true, qid, indices,
                                            num_pos, num_item, ideal_dcg,
                                            u_buf, v_buf, lambda_q, r_q, s_q, ws);
    ndcg_final_kernel<<<1, 64, 0, stream>>>(ws, (float*)d_out);
}